// Round 11
// baseline (21.180 us; speedup 1.0000x reference)
//
#include <hip/hip_runtime.h>
#include <math.h>

#define DD       768
#define HDIM     512
#define TOKDIM   256
#define LOCALDIM 16384
#define FEATDIM  16640            // 16384 + 256
#define BB       64
#define THRESH   0.7f
#define ONEF     0x3f800000u      // bit pattern of 1.0f

// ws float offsets
#define WS_H     0                // h[64][512] post-ReLU
#define WS_G     (BB*HDIM)        // g[64][256] final

// NetVLAD local branch is identically 1.0 (softmax(axis=1).sum(axis=1) == 1),
// so feats = [inv * ones(16384), g/norm], norm = sqrt(16384 + ||g||^2), and
// sim_ij = (16384 + g_i.g_j) * inv_i * inv_j.

// ---- K1: h = relu(x@W1+b1). 256 blocks = 16 batch-groups x 16 unit-chunks.
// Block: 4 batches x 32 units x full 768 d. Per-block global reads: 96 KB W1
// (amortized over 4 batches in registers) + 12 KB x.
__global__ __launch_bounds__(1024) void k1_h(
    const float* __restrict__ gtok, const float* __restrict__ W1,
    const float* __restrict__ b1,   float* __restrict__ ws,
    unsigned* __restrict__ maskU)
{
    __shared__ float  xs[4][DD];      // 12 KB
    __shared__ float4 hh[128][33];    // [q][u4*4+bb], padded stride 33 (66 KB)
    __shared__ float  pr[8][128];     // fold stage (4 KB)
    const int blk = blockIdx.x, t = threadIdx.x;
    const int bg = blk >> 4, uc = blk & 15;
    const int b0 = bg * 4, u0 = uc * 32;

    if (blk == 0) {                   // zero mask; 2 graph edges before K3's ORs
        maskU[t] = 0u; maskU[t+1024] = 0u; maskU[t+2048] = 0u; maskU[t+3072] = 0u;
    }
    if (t < DD) {
        xs[0][t] = gtok[(size_t)(b0+0)*DD + t];
        xs[1][t] = gtok[(size_t)(b0+1)*DD + t];
        xs[2][t] = gtok[(size_t)(b0+2)*DD + t];
        xs[3][t] = gtok[(size_t)(b0+3)*DD + t];
    }
    __syncthreads();

    // thread = 4 units (float4) x 4 batches x 6-d slice -> 6 loads, 96 fma
    {
        const int u4 = t & 7, q = t >> 3;        // q: 128 slices of 6 d
        const int d0 = q * 6;
        const float4* w = (const float4*)W1 + (size_t)d0 * 128 + uc * 8 + u4;
        float4 a0 = {0,0,0,0}, a1 = {0,0,0,0}, a2 = {0,0,0,0}, a3 = {0,0,0,0};
        #pragma unroll
        for (int d = 0; d < 6; ++d) {
            const float4 wv = w[(size_t)d * 128];
            const float x0 = xs[0][d0+d], x1 = xs[1][d0+d];
            const float x2 = xs[2][d0+d], x3 = xs[3][d0+d];
            a0.x = fmaf(x0, wv.x, a0.x); a0.y = fmaf(x0, wv.y, a0.y);
            a0.z = fmaf(x0, wv.z, a0.z); a0.w = fmaf(x0, wv.w, a0.w);
            a1.x = fmaf(x1, wv.x, a1.x); a1.y = fmaf(x1, wv.y, a1.y);
            a1.z = fmaf(x1, wv.z, a1.z); a1.w = fmaf(x1, wv.w, a1.w);
            a2.x = fmaf(x2, wv.x, a2.x); a2.y = fmaf(x2, wv.y, a2.y);
            a2.z = fmaf(x2, wv.z, a2.z); a2.w = fmaf(x2, wv.w, a2.w);
            a3.x = fmaf(x3, wv.x, a3.x); a3.y = fmaf(x3, wv.y, a3.y);
            a3.z = fmaf(x3, wv.z, a3.z); a3.w = fmaf(x3, wv.w, a3.w);
        }
        hh[q][u4*4+0] = a0; hh[q][u4*4+1] = a1;
        hh[q][u4*4+2] = a2; hh[q][u4*4+3] = a3;
    }
    __syncthreads();

    // fold 128 q -> 8 (flat col c = u4*16 + bb*4 + comp; stride 132 floats)
    {
        const float* hhf = (const float*)hh;
        const int c = t & 127, qg = t >> 7;
        float s = 0.f;
        #pragma unroll
        for (int qq = 0; qq < 16; ++qq) s += hhf[(size_t)(qg*16+qq)*132 + c];
        pr[qg][c] = s;
    }
    __syncthreads();
    if (t < 128) {                    // c=t -> (u4=t>>4, bb=(t>>2)&3, comp=t&3)
        const int u = ((t >> 4) << 2) | (t & 3), bb = (t >> 2) & 3;
        float s = b1[u0 + u];
        #pragma unroll
        for (int qg = 0; qg < 8; ++qg) s += pr[qg][t];
        ws[WS_H + (size_t)(b0+bb)*HDIM + u0 + u] = fmaxf(s, 0.f);
    }
}

// ---- K2: g = h@W2+b2. 256 blocks = 16 batch-groups x 16 out-chunks.
// Per-block global reads: 8 KB h + 32 KB W2-slice (amortized over 4 batches).
__global__ __launch_bounds__(256) void k2_g(
    const float* __restrict__ W2, const float* __restrict__ b2,
    float* __restrict__ ws)
{
    __shared__ float  hsm[4][HDIM];   // 8 KB
    __shared__ float4 gg[64][17];     // [jq][o4*4+bb], padded (17.4 KB)
    const int blk = blockIdx.x, t = threadIdx.x;
    const int bg = blk >> 4, og = blk & 15;
    const int b0 = bg * 4, o0 = og * 16;

    for (int i = t; i < 4*HDIM; i += 256)
        hsm[i >> 9][i & 511] = ws[WS_H + (size_t)(b0 + (i >> 9))*HDIM + (i & 511)];
    __syncthreads();

    // thread = 4 outs (float4) x 4 batches x 8-j slice -> 8 loads, 128 fma
    {
        const int o4 = t & 3, jq = t >> 2;       // 64 slices of 8 j
        const float4* w = (const float4*)W2 + (size_t)(jq*8)*64 + og*4 + o4;
        float4 a0 = {0,0,0,0}, a1 = {0,0,0,0}, a2 = {0,0,0,0}, a3 = {0,0,0,0};
        #pragma unroll
        for (int j = 0; j < 8; ++j) {
            const float4 wv = w[(size_t)j * 64];
            const int jj = jq*8 + j;
            const float h0 = hsm[0][jj], h1 = hsm[1][jj];
            const float h2 = hsm[2][jj], h3 = hsm[3][jj];
            a0.x = fmaf(h0, wv.x, a0.x); a0.y = fmaf(h0, wv.y, a0.y);
            a0.z = fmaf(h0, wv.z, a0.z); a0.w = fmaf(h0, wv.w, a0.w);
            a1.x = fmaf(h1, wv.x, a1.x); a1.y = fmaf(h1, wv.y, a1.y);
            a1.z = fmaf(h1, wv.z, a1.z); a1.w = fmaf(h1, wv.w, a1.w);
            a2.x = fmaf(h2, wv.x, a2.x); a2.y = fmaf(h2, wv.y, a2.y);
            a2.z = fmaf(h2, wv.z, a2.z); a2.w = fmaf(h2, wv.w, a2.w);
            a3.x = fmaf(h3, wv.x, a3.x); a3.y = fmaf(h3, wv.y, a3.y);
            a3.z = fmaf(h3, wv.z, a3.z); a3.w = fmaf(h3, wv.w, a3.w);
        }
        gg[jq][o4*4+0] = a0; gg[jq][o4*4+1] = a1;
        gg[jq][o4*4+2] = a2; gg[jq][o4*4+3] = a3;
    }
    __syncthreads();
    if (t < 64) {                     // c=t -> (o4=t>>4, bb=(t>>2)&3, comp=t&3)
        const int o = ((t >> 4) << 2) | (t & 3), bb = (t >> 2) & 3;
        const float* ggf = (const float*)gg;
        float s = b2[o0 + o];
        #pragma unroll
        for (int jq = 0; jq < 64; ++jq) s += ggf[(size_t)jq*68 + t];
        ws[WS_G + (size_t)(b0+bb)*TOKDIM + o0 + o] = s;
    }
}

// ---- K3: 64 blocks. Block i: all inv-norms from g (64 KB, L2-hot), feats
// row i (fill + gn), sim row i, top-k, idempotent mask ORs. ----
__global__ __launch_bounds__(1024) void k3_simmask(
    const float* __restrict__ ws, const int* __restrict__ kptr,
    float* __restrict__ feats,    unsigned* __restrict__ maskU)
{
    __shared__ float gT[TOKDIM][BB + 1];   // stride 65: conflict-free both ways
    __shared__ float part[16][BB];
    __shared__ float invs[BB];
    const int i = blockIdx.x, t = threadIdx.x;

    // FIX (R10 bug): load ALL 16384 elements of g (16 rounds, j in [0,64)),
    // not 4 rounds / j in [0,16).
    #pragma unroll
    for (int r = 0; r < 16; ++r) {
        const int idx = r*1024 + t, j = idx >> 8, d = idx & 255;
        gT[d][j] = ws[WS_G + (size_t)j*TOKDIM + d];
    }
    __syncthreads();

    {   // ||g_j||^2 partials
        const int q = t >> 6, j = t & 63;
        float s = 0.f;
        #pragma unroll
        for (int dd = 0; dd < 16; ++dd) { const float v = gT[q*16+dd][j]; s = fmaf(v, v, s); }
        part[q][j] = s;
    }
    __syncthreads();
    if (t < BB) {
        float ssq = 0.f;
        #pragma unroll
        for (int q = 0; q < 16; ++q) ssq += part[q][t];
        invs[t] = 1.f / fmaxf(sqrtf((float)LOCALDIM + ssq), 1e-12f);
    }
    __syncthreads();
    const float inv = invs[i];

    // feats row i: 16384-wide inv fill + normalized g
    {
        float4* f4 = (float4*)(feats + (size_t)i * FEATDIM);
        const float4 v = make_float4(inv, inv, inv, inv);
        f4[t] = v; f4[t + 1024] = v; f4[t + 2048] = v; f4[t + 3072] = v;
        if (t < TOKDIM) feats[(size_t)i * FEATDIM + LOCALDIM + t] = gT[t][i] * inv;
    }
    __syncthreads();

    {   // sim row i partials: gT[d][i] broadcast x gT[d][j] conflict-free
        const int q = t >> 6, j = t & 63;
        float s = 0.f;
        #pragma unroll
        for (int dd = 0; dd < 16; ++dd)
            s = fmaf(gT[q*16+dd][i], gT[q*16+dd][j], s);
        part[q][j] = s;
    }
    __syncthreads();
    if (t < BB) {                     // wave 0: full 64-lane wave
        float dot = 0.f;
        #pragma unroll
        for (int q = 0; q < 16; ++q) dot += part[q][t];
        const float sv = ((float)LOCALDIM + dot) * inv * invs[t];
        int k = *kptr; if (k > BB) k = BB;
        float v = sv;
        unsigned long long rowbits = 0;
        for (int p = 0; p < k; ++p) {  // ties -> lowest index (jax top_k)
            float m = v;
            #pragma unroll
            for (int off = 32; off > 0; off >>= 1) m = fmaxf(m, __shfl_xor(m, off));
            const unsigned long long ball = __ballot(v == m);
            const int bi = __ffsll(ball) - 1;
            rowbits |= 1ull << bi;
            if (t == bi) v = -INFINITY;
            if (t == 0) atomicOr(&maskU[bi * BB + i], ONEF);   // mask[idx, row] = 1
        }
        const unsigned base =
            ((sv > THRESH) || (t == i) || ((rowbits >> t) & 1ull)) ? ONEF : 0u;
        if (base) atomicOr(&maskU[i * BB + t], base);          // row i
    }
}

extern "C" void kernel_launch(void* const* d_in, const int* in_sizes, int n_in,
                              void* d_out, int out_size, void* d_ws, size_t ws_size,
                              hipStream_t stream) {
    const float* gtok = (const float*)d_in[1];
    const float* W1g  = (const float*)d_in[6];
    const float* b1g  = (const float*)d_in[7];
    const float* W2g  = (const float*)d_in[8];
    const float* b2g  = (const float*)d_in[9];
    const int*   kp   = (const int*)d_in[10];

    float*    feats = (float*)d_out;                              // [64, 16640]
    unsigned* maskU = (unsigned*)(feats + (size_t)BB * FEATDIM);  // [64,64] as bits
    float*    ws    = (float*)d_ws;

    hipLaunchKernelGGL(k1_h,       dim3(256), dim3(1024), 0, stream,
                       gtok, W1g, b1g, ws, maskU);
    hipLaunchKernelGGL(k2_g,       dim3(256), dim3(256),  0, stream,
                       W2g, b2g, ws);
    hipLaunchKernelGGL(k3_simmask, dim3(BB),  dim3(1024), 0, stream,
                       ws, kp, feats, maskU);
}